// Round 12
// baseline (99.765 us; speedup 1.0000x reference)
//
#include <hip/hip_runtime.h>

#define EPS 1e-8f
#define THR 0.65f

constexpr int DIM  = 1024;
constexpr int SEQ  = 2048;
constexpr int NMEM = 131072;

constexpr int SIM_BLKS = 8192;  // sim grid; one best per block (A/B vs 4096)
constexpr int ROWS_PER_WAVE = NMEM / (SIM_BLKS * 4);  // 4

typedef float f4 __attribute__((ext_vector_type(4)));

// ws layout (float indices):
//   [0 .. 262144)        partial[256][1024] row-sums (plain stores, no init)
//   [262144 .. 263168)   q mean [1024]
//   [263168 .. 263176)   ssp[8] per-block sum-sq partials of q
//   [263178 .. 279562)   bests[8192] as u64 (byte 1052712, 8-aligned)
constexpr int WS_Q     = 262144;
constexpr int WS_SSP   = 263168;
constexpr int WS_BESTS = 263178;

// grid: 256 x 256. Block b sums query rows [8b, 8b+8); thread t owns f4-col t.
// Plain store to partial[b] — no init, no atomics, no fences.
__global__ void qsumA_kernel(const float* __restrict__ query, float* __restrict__ ws) {
    int t = threadIdx.x;
    int b = blockIdx.x;
    const f4* qp = (const f4*)(query + (size_t)b * 8 * DIM) + t;
    f4 s = __builtin_nontemporal_load(qp);
    #pragma unroll
    for (int r = 1; r < 8; ++r) s += __builtin_nontemporal_load(qp + r * 256);
    ((f4*)ws)[b * 256 + t] = s;
}

// grid: 8 x 256. Block j owns f4-cols [32j, 32j+32): folds 256 partials,
// scales by 1/SEQ, writes q-mean cols + its sum-sq partial ssp[j].
__global__ void qsumB_kernel(float* __restrict__ ws) {
    __shared__ f4 lds[256];
    int t = threadIdx.x;
    int j = blockIdx.x;
    int fc    = 32 * j + (t & 31);
    int chunk = t >> 5;
    const f4* pf = (const f4*)ws;
    f4 s = pf[(32 * chunk) * 256 + fc];
    #pragma unroll
    for (int i = 1; i < 32; ++i) s += pf[(32 * chunk + i) * 256 + fc];
    lds[t] = s;
    __syncthreads();
    if (t < 32) {
        f4 f = lds[t];
        #pragma unroll
        for (int c = 1; c < 8; ++c) f += lds[t + 32 * c];
        f *= (1.0f / (float)SEQ);
        ((f4*)(ws + WS_Q))[32 * j + t] = f;
        float ss = f.x * f.x + f.y * f.y + f.z * f.z + f.w * f.w;
        #pragma unroll
        for (int m = 16; m >= 1; m >>= 1) ss += __shfl_xor(ss, m);
        if (t == 0) ws[WS_SSP + j] = ss;
    }
}

__device__ __forceinline__ unsigned int float_to_ordered(float f) {
    unsigned int b = __float_as_uint(f);
    return (b & 0x80000000u) ? ~b : (b | 0x80000000u);
}

__device__ __forceinline__ unsigned long long pack_best(float sim, int idx) {
    return ((unsigned long long)float_to_ordered(sim) << 32) |
           (unsigned int)(~(unsigned int)idx);   // ~idx: ties -> smaller idx
}

// grid: SIM_BLKS x 256 (4 waves). Each wave owns ROWS_PER_WAVE CONSECUTIVE
// rows. Body identical to the proven R9/R11 kernel; only the grid knob moves.
__launch_bounds__(256)
__global__ void sim_kernel(const float* __restrict__ bank, const float* __restrict__ ws,
                           unsigned long long* __restrict__ bests) {
    __shared__ unsigned long long wbest[4];
    int tid  = threadIdx.x;
    int lane = tid & 63;
    int wid  = tid >> 6;

    // qn from the 8 sum-sq partials (broadcast L2 loads)
    float ssq = ws[WS_SSP + 0];
    #pragma unroll
    for (int j = 1; j < 8; ++j) ssq += ws[WS_SSP + j];
    float qn = fmaxf(sqrtf(ssq), EPS);

    // hoist q fragment: 4 x f4 per lane, loop-invariant
    const f4* q4 = (const f4*)(ws + WS_Q);
    f4 q0 = q4[lane +   0];
    f4 q1 = q4[lane +  64];
    f4 q2 = q4[lane + 128];
    f4 q3 = q4[lane + 192];

    int gw   = blockIdx.x * 4 + wid;
    int row0 = gw * ROWS_PER_WAVE;

    float bestSim = -1e30f;
    int   bestIdx = 0;

    #pragma unroll
    for (int g = 0; g < ROWS_PER_WAVE / 4; ++g) {
        float dot[4], ss[4];
        f4 b[4][4];
        #pragma unroll
        for (int r = 0; r < 4; ++r) {
            const f4* bp = (const f4*)(bank + (size_t)(row0 + g * 4 + r) * DIM);
            b[r][0] = __builtin_nontemporal_load(bp + lane +   0);
            b[r][1] = __builtin_nontemporal_load(bp + lane +  64);
            b[r][2] = __builtin_nontemporal_load(bp + lane + 128);
            b[r][3] = __builtin_nontemporal_load(bp + lane + 192);
        }
        #pragma unroll
        for (int r = 0; r < 4; ++r) {
            dot[r] = b[r][0].x*q0.x + b[r][0].y*q0.y + b[r][0].z*q0.z + b[r][0].w*q0.w
                   + b[r][1].x*q1.x + b[r][1].y*q1.y + b[r][1].z*q1.z + b[r][1].w*q1.w
                   + b[r][2].x*q2.x + b[r][2].y*q2.y + b[r][2].z*q2.z + b[r][2].w*q2.w
                   + b[r][3].x*q3.x + b[r][3].y*q3.y + b[r][3].z*q3.z + b[r][3].w*q3.w;
            ss[r]  = b[r][0].x*b[r][0].x + b[r][0].y*b[r][0].y + b[r][0].z*b[r][0].z + b[r][0].w*b[r][0].w
                   + b[r][1].x*b[r][1].x + b[r][1].y*b[r][1].y + b[r][1].z*b[r][1].z + b[r][1].w*b[r][1].w
                   + b[r][2].x*b[r][2].x + b[r][2].y*b[r][2].y + b[r][2].z*b[r][2].z + b[r][2].w*b[r][2].w
                   + b[r][3].x*b[r][3].x + b[r][3].y*b[r][3].y + b[r][3].z*b[r][3].z + b[r][3].w*b[r][3].w;
        }
        #pragma unroll
        for (int m = 32; m >= 1; m >>= 1) {
            #pragma unroll
            for (int r = 0; r < 4; ++r) {
                dot[r] += __shfl_xor(dot[r], m);
                ss[r]  += __shfl_xor(ss[r], m);
            }
        }
        #pragma unroll
        for (int r = 0; r < 4; ++r) {
            float bn  = fmaxf(sqrtf(ss[r]), EPS);
            float sim = dot[r] / (bn * qn);
            if (sim > bestSim) { bestSim = sim; bestIdx = row0 + g * 4 + r; }
        }
    }

    if (lane == 0) wbest[wid] = pack_best(bestSim, bestIdx);
    __syncthreads();
    if (tid == 0) {
        unsigned long long p = wbest[0];
        if (wbest[1] > p) p = wbest[1];
        if (wbest[2] > p) p = wbest[2];
        if (wbest[3] > p) p = wbest[3];
        bests[blockIdx.x] = p;
    }
}

// grid: 256 x 256 (4 waves). Each block redundantly reduces bests[8192]
// (L2-resident) via wave shuffles (1 sync), then one wave per output row.
__global__ void decode_kernel(const float* __restrict__ bank,
                              const float* __restrict__ w_dec,
                              const float* __restrict__ b_dec,
                              const unsigned long long* __restrict__ bests,
                              float* __restrict__ out) {
    __shared__ unsigned long long wred[4];
    __shared__ float mem[DIM];
    int tid = threadIdx.x;
    int lane = tid & 63, wid = tid >> 6;

    unsigned long long p = bests[tid];
    #pragma unroll
    for (int i = 1; i < SIM_BLKS / 256; ++i) {
        unsigned long long v = bests[tid + i * 256];
        if (v > p) p = v;
    }
    #pragma unroll
    for (int m = 32; m >= 1; m >>= 1) {
        unsigned long long v = __shfl_xor(p, m);
        if (v > p) p = v;
    }
    if (lane == 0) wred[wid] = p;
    __syncthreads();
    p = wred[0];
    if (wred[1] > p) p = wred[1];
    if (wred[2] > p) p = wred[2];
    if (wred[3] > p) p = wred[3];

    unsigned int u = (unsigned int)(p >> 32);
    unsigned int fb = (u & 0x80000000u) ? (u & 0x7FFFFFFFu) : ~u;
    float sim = __uint_as_float(fb);
    int idx   = (int)(~(unsigned int)(p & 0xFFFFFFFFu));

    ((float4*)mem)[tid] = ((const float4*)(bank + (size_t)idx * DIM))[tid];
    __syncthreads();

    bool ok = sim > THR;
    int row = blockIdx.x * 4 + wid;

    const float4* wp = (const float4*)(w_dec + (size_t)row * DIM);
    const float4* m4 = (const float4*)mem;
    float dot = 0.f;
    #pragma unroll
    for (int it = 0; it < 4; ++it) {
        float4 w = wp[lane + it * 64];
        float4 m = m4[lane + it * 64];
        dot += w.x * m.x + w.y * m.y + w.z * m.z + w.w * m.w;
    }
    #pragma unroll
    for (int m = 32; m >= 1; m >>= 1) dot += __shfl_xor(dot, m);

    if (lane == 0) out[row] = ok ? (dot + b_dec[row]) : 0.0f;
}

extern "C" void kernel_launch(void* const* d_in, const int* in_sizes, int n_in,
                              void* d_out, int out_size, void* d_ws, size_t ws_size,
                              hipStream_t stream) {
    const float* query = (const float*)d_in[0];
    const float* bank  = (const float*)d_in[1];
    const float* w_dec = (const float*)d_in[2];
    const float* b_dec = (const float*)d_in[3];
    float* out = (float*)d_out;
    float* ws  = (float*)d_ws;
    unsigned long long* bests = (unsigned long long*)(ws + WS_BESTS);

    qsumA_kernel<<<256, 256, 0, stream>>>(query, ws);
    qsumB_kernel<<<8, 256, 0, stream>>>(ws);
    sim_kernel<<<SIM_BLKS, 256, 0, stream>>>(bank, ws, bests);
    decode_kernel<<<256, 256, 0, stream>>>(bank, w_dec, b_dec, bests, out);
}

// Round 13
// 98.072 us; speedup vs baseline: 1.0173x; 1.0173x over previous
//
#include <hip/hip_runtime.h>

#define EPS 1e-8f
#define THR 0.65f

constexpr int DIM  = 1024;
constexpr int SEQ  = 2048;
constexpr int NMEM = 131072;

constexpr int SIM_BLKS = 4096;  // sim grid; EMPIRICAL OPTIMUM (R11: 98.3 us;
                                // 2048 -> 104.5, 8192 -> 99.8)
constexpr int ROWS_PER_WAVE = NMEM / (SIM_BLKS * 4);  // 8

typedef float f4 __attribute__((ext_vector_type(4)));

// ws layout (float indices):
//   [0 .. 262144)        partial[256][1024] row-sums (plain stores, no init)
//   [262144 .. 263168)   q mean [1024]
//   [263168 .. 263176)   ssp[8] per-block sum-sq partials of q
//   [263178 .. 271370)   bests[4096] as u64 (byte 1052712, 8-aligned)
constexpr int WS_Q     = 262144;
constexpr int WS_SSP   = 263168;
constexpr int WS_BESTS = 263178;

// grid: 256 x 256. Block b sums query rows [8b, 8b+8); thread t owns f4-col t.
// Plain store to partial[b] — no init, no atomics, no fences.
__global__ void qsumA_kernel(const float* __restrict__ query, float* __restrict__ ws) {
    int t = threadIdx.x;
    int b = blockIdx.x;
    const f4* qp = (const f4*)(query + (size_t)b * 8 * DIM) + t;
    f4 s = __builtin_nontemporal_load(qp);
    #pragma unroll
    for (int r = 1; r < 8; ++r) s += __builtin_nontemporal_load(qp + r * 256);
    ((f4*)ws)[b * 256 + t] = s;
}

// grid: 8 x 256. Block j owns f4-cols [32j, 32j+32): folds 256 partials,
// scales by 1/SEQ, writes q-mean cols + its sum-sq partial ssp[j].
__global__ void qsumB_kernel(float* __restrict__ ws) {
    __shared__ f4 lds[256];
    int t = threadIdx.x;
    int j = blockIdx.x;
    int fc    = 32 * j + (t & 31);
    int chunk = t >> 5;
    const f4* pf = (const f4*)ws;
    f4 s = pf[(32 * chunk) * 256 + fc];
    #pragma unroll
    for (int i = 1; i < 32; ++i) s += pf[(32 * chunk + i) * 256 + fc];
    lds[t] = s;
    __syncthreads();
    if (t < 32) {
        f4 f = lds[t];
        #pragma unroll
        for (int c = 1; c < 8; ++c) f += lds[t + 32 * c];
        f *= (1.0f / (float)SEQ);
        ((f4*)(ws + WS_Q))[32 * j + t] = f;
        float ss = f.x * f.x + f.y * f.y + f.z * f.z + f.w * f.w;
        #pragma unroll
        for (int m = 16; m >= 1; m >>= 1) ss += __shfl_xor(ss, m);
        if (t == 0) ws[WS_SSP + j] = ss;
    }
}

__device__ __forceinline__ unsigned int float_to_ordered(float f) {
    unsigned int b = __float_as_uint(f);
    return (b & 0x80000000u) ? ~b : (b | 0x80000000u);
}

__device__ __forceinline__ unsigned long long pack_best(float sim, int idx) {
    return ((unsigned long long)float_to_ordered(sim) << 32) |
           (unsigned int)(~(unsigned int)idx);   // ~idx: ties -> smaller idx
}

// grid: SIM_BLKS x 256 (4 waves). Each wave owns 8 CONSECUTIVE rows.
// nt loads (A/B-proven +11 us), ssp-sum qn, plain per-block best store.
__launch_bounds__(256)
__global__ void sim_kernel(const float* __restrict__ bank, const float* __restrict__ ws,
                           unsigned long long* __restrict__ bests) {
    __shared__ unsigned long long wbest[4];
    int tid  = threadIdx.x;
    int lane = tid & 63;
    int wid  = tid >> 6;

    // qn from the 8 sum-sq partials (broadcast L2 loads)
    float ssq = ws[WS_SSP + 0];
    #pragma unroll
    for (int j = 1; j < 8; ++j) ssq += ws[WS_SSP + j];
    float qn = fmaxf(sqrtf(ssq), EPS);

    // hoist q fragment: 4 x f4 per lane, loop-invariant
    const f4* q4 = (const f4*)(ws + WS_Q);
    f4 q0 = q4[lane +   0];
    f4 q1 = q4[lane +  64];
    f4 q2 = q4[lane + 128];
    f4 q3 = q4[lane + 192];

    int gw   = blockIdx.x * 4 + wid;
    int row0 = gw * ROWS_PER_WAVE;

    float bestSim = -1e30f;
    int   bestIdx = 0;

    #pragma unroll
    for (int g = 0; g < ROWS_PER_WAVE / 4; ++g) {
        float dot[4], ss[4];
        f4 b[4][4];
        #pragma unroll
        for (int r = 0; r < 4; ++r) {
            const f4* bp = (const f4*)(bank + (size_t)(row0 + g * 4 + r) * DIM);
            b[r][0] = __builtin_nontemporal_load(bp + lane +   0);
            b[r][1] = __builtin_nontemporal_load(bp + lane +  64);
            b[r][2] = __builtin_nontemporal_load(bp + lane + 128);
            b[r][3] = __builtin_nontemporal_load(bp + lane + 192);
        }
        #pragma unroll
        for (int r = 0; r < 4; ++r) {
            dot[r] = b[r][0].x*q0.x + b[r][0].y*q0.y + b[r][0].z*q0.z + b[r][0].w*q0.w
                   + b[r][1].x*q1.x + b[r][1].y*q1.y + b[r][1].z*q1.z + b[r][1].w*q1.w
                   + b[r][2].x*q2.x + b[r][2].y*q2.y + b[r][2].z*q2.z + b[r][2].w*q2.w
                   + b[r][3].x*q3.x + b[r][3].y*q3.y + b[r][3].z*q3.z + b[r][3].w*q3.w;
            ss[r]  = b[r][0].x*b[r][0].x + b[r][0].y*b[r][0].y + b[r][0].z*b[r][0].z + b[r][0].w*b[r][0].w
                   + b[r][1].x*b[r][1].x + b[r][1].y*b[r][1].y + b[r][1].z*b[r][1].z + b[r][1].w*b[r][1].w
                   + b[r][2].x*b[r][2].x + b[r][2].y*b[r][2].y + b[r][2].z*b[r][2].z + b[r][2].w*b[r][2].w
                   + b[r][3].x*b[r][3].x + b[r][3].y*b[r][3].y + b[r][3].z*b[r][3].z + b[r][3].w*b[r][3].w;
        }
        #pragma unroll
        for (int m = 32; m >= 1; m >>= 1) {
            #pragma unroll
            for (int r = 0; r < 4; ++r) {
                dot[r] += __shfl_xor(dot[r], m);
                ss[r]  += __shfl_xor(ss[r], m);
            }
        }
        #pragma unroll
        for (int r = 0; r < 4; ++r) {
            float bn  = fmaxf(sqrtf(ss[r]), EPS);
            float sim = dot[r] / (bn * qn);
            if (sim > bestSim) { bestSim = sim; bestIdx = row0 + g * 4 + r; }
        }
    }

    if (lane == 0) wbest[wid] = pack_best(bestSim, bestIdx);
    __syncthreads();
    if (tid == 0) {
        unsigned long long p = wbest[0];
        if (wbest[1] > p) p = wbest[1];
        if (wbest[2] > p) p = wbest[2];
        if (wbest[3] > p) p = wbest[3];
        bests[blockIdx.x] = p;
    }
}

// grid: 256 x 256 (4 waves). Each block redundantly reduces bests[4096]
// (L2-resident) via wave shuffles (1 sync), then one wave per output row.
__global__ void decode_kernel(const float* __restrict__ bank,
                              const float* __restrict__ w_dec,
                              const float* __restrict__ b_dec,
                              const unsigned long long* __restrict__ bests,
                              float* __restrict__ out) {
    __shared__ unsigned long long wred[4];
    __shared__ float mem[DIM];
    int tid = threadIdx.x;
    int lane = tid & 63, wid = tid >> 6;

    unsigned long long p = bests[tid];
    #pragma unroll
    for (int i = 1; i < SIM_BLKS / 256; ++i) {
        unsigned long long v = bests[tid + i * 256];
        if (v > p) p = v;
    }
    #pragma unroll
    for (int m = 32; m >= 1; m >>= 1) {
        unsigned long long v = __shfl_xor(p, m);
        if (v > p) p = v;
    }
    if (lane == 0) wred[wid] = p;
    __syncthreads();
    p = wred[0];
    if (wred[1] > p) p = wred[1];
    if (wred[2] > p) p = wred[2];
    if (wred[3] > p) p = wred[3];

    unsigned int u = (unsigned int)(p >> 32);
    unsigned int fb = (u & 0x80000000u) ? (u & 0x7FFFFFFFu) : ~u;
    float sim = __uint_as_float(fb);
    int idx   = (int)(~(unsigned int)(p & 0xFFFFFFFFu));

    ((float4*)mem)[tid] = ((const float4*)(bank + (size_t)idx * DIM))[tid];
    __syncthreads();

    bool ok = sim > THR;
    int row = blockIdx.x * 4 + wid;

    const float4* wp = (const float4*)(w_dec + (size_t)row * DIM);
    const float4* m4 = (const float4*)mem;
    float dot = 0.f;
    #pragma unroll
    for (int it = 0; it < 4; ++it) {
        float4 w = wp[lane + it * 64];
        float4 m = m4[lane + it * 64];
        dot += w.x * m.x + w.y * m.y + w.z * m.z + w.w * m.w;
    }
    #pragma unroll
    for (int m = 32; m >= 1; m >>= 1) dot += __shfl_xor(dot, m);

    if (lane == 0) out[row] = ok ? (dot + b_dec[row]) : 0.0f;
}

extern "C" void kernel_launch(void* const* d_in, const int* in_sizes, int n_in,
                              void* d_out, int out_size, void* d_ws, size_t ws_size,
                              hipStream_t stream) {
    const float* query = (const float*)d_in[0];
    const float* bank  = (const float*)d_in[1];
    const float* w_dec = (const float*)d_in[2];
    const float* b_dec = (const float*)d_in[3];
    float* out = (float*)d_out;
    float* ws  = (float*)d_ws;
    unsigned long long* bests = (unsigned long long*)(ws + WS_BESTS);

    qsumA_kernel<<<256, 256, 0, stream>>>(query, ws);
    qsumB_kernel<<<8, 256, 0, stream>>>(ws);
    sim_kernel<<<SIM_BLKS, 256, 0, stream>>>(bank, ws, bests);
    decode_kernel<<<256, 256, 0, stream>>>(bank, w_dec, b_dec, bests, out);
}